// Round 12
// baseline (169.576 us; speedup 1.0000x reference)
//
#include <hip/hip_runtime.h>
#include <hip/hip_cooperative_groups.h>
#include <math.h>

namespace cg = cooperative_groups;

#define B_ 8
#define L_ 16
#define M_ 256
#define H_ 53
#define HID_ 64
#define LB_ 128  // L_*B_
#define SCALE_ 0.08838834764831845f

typedef __attribute__((ext_vector_type(8))) short bf16x8;
typedef __attribute__((ext_vector_type(4))) float f32x4;

__device__ inline unsigned short f2bf(float f) {
  unsigned u = __builtin_bit_cast(unsigned, f);
  unsigned r = (u + 0x7FFFu + ((u >> 16) & 1u)) >> 16;
  return (unsigned short)r;
}
__device__ inline float bf2f(unsigned short u) {
  unsigned v = ((unsigned)u) << 16;
  return __builtin_bit_cast(float, v);
}
__device__ inline float sigm(float x) { return __builtin_amdgcn_rcpf(1.f + __expf(-x)); }
__device__ inline float ftanh(float x) { return 1.f - 2.f * __builtin_amdgcn_rcpf(1.f + __expf(2.f * x)); }

// ================= MEGA cooperative kernel: P | A | B | R with 3 grid syncs =================
__global__ __launch_bounds__(512, 2) void kMega(
    const float* __restrict__ x,
    const float* __restrict__ Wa, const float* __restrict__ Wg,
    const float* __restrict__ ba, const float* __restrict__ bg,
    const float* __restrict__ Qw, const float* __restrict__ Kw,
    const int* __restrict__ Gmat, const float* __restrict__ Wih_c,
    const float* __restrict__ W2, const float* __restrict__ b2,
    const float* __restrict__ Whh_a, const float* __restrict__ Whh_c,
    const float* __restrict__ Wih_a,
    const float* __restrict__ bih_a, const float* __restrict__ bhh_a,
    const float* __restrict__ bih_c, const float* __restrict__ bhh_c,
    const int* __restrict__ action,
    const float* __restrict__ Wma1, const float* __restrict__ bma1,
    const float* __restrict__ Wma2, const float* __restrict__ bma2,
    const float* __restrict__ Wmc1, const float* __restrict__ bmc1,
    const float* __restrict__ Wmc2, const float* __restrict__ bmc2,
    unsigned short* __restrict__ WQ_b, unsigned short* __restrict__ WK_b,
    float* __restrict__ bqk, unsigned short* __restrict__ Wab_b,
    unsigned short* __restrict__ a_lin_bf, unsigned short* __restrict__ s_b,
    unsigned short* __restrict__ q_b, unsigned short* __restrict__ k_b,
    unsigned short* __restrict__ sT_b, unsigned short* __restrict__ so_b,
    unsigned short* __restrict__ Wfold_b, float* __restrict__ bias_fold,
    unsigned* __restrict__ gmask,
    unsigned short* __restrict__ Whha_b, unsigned short* __restrict__ Whhc_b,
    unsigned short* __restrict__ Wiha_b, float* __restrict__ out) {
  __shared__ __attribute__((aligned(16))) char smem[140288];
  cg::grid_group grid = cg::this_grid();
  int blk = blockIdx.x, tid = threadIdx.x;

  // ---------------- Phase P: one-time precomputes + extras ----------------
  if (tid < 256) {
    int t = tid;
    if (blk < 32) {                       // WQ/WK [64][64]
      int idx = blk * 256 + t;
      int which = idx >> 12, n = (idx >> 6) & 63, j = idx & 63;
      const float* Mm = which ? Kw : Qw;
      float acc = 0.f;
      if (j < 53) {
        for (int e = 0; e < 64; ++e) acc = fmaf(Mm[e * 64 + n], Wg[e * 53 + j], acc);
        if (which == 0) acc *= SCALE_;
      }
      (which ? WK_b : WQ_b)[n * 64 + j] = f2bf(acc);
    } else if (blk == 32) {               // bqk + bias_fold
      if (t < 128) {
        int which = t >> 6, n = t & 63;
        const float* Mm = which ? Kw : Qw;
        float acc = 0.f;
        for (int e = 0; e < 64; ++e) acc = fmaf(bg[e], Mm[e * 64 + n], acc);
        if (which == 0) acc *= SCALE_;
        bqk[t] = acc;
      }
      float bacc = 0.f;
      for (int e = 0; e < 64; ++e) bacc = fmaf(Wih_c[t * 64 + e], b2[e], bacc);
      bias_fold[t] = bacc;
    } else if (blk < 35) {                // Wab
      int base = (blk - 33) * 4096;
      #pragma unroll
      for (int k = 0; k < 16; ++k) {
        int idx = base + k * 256 + t;
        int n = idx >> 6, j = idx & 63;
        float v = 0.f;
        if (j < 53) v = (n < 64) ? Wa[n * 53 + j] : Wg[(n - 64) * 53 + j];
        Wab_b[idx] = f2bf(v);
      }
    } else if (blk < 163) {               // Wfold (128 blocks)
      int idx = (blk - 35) * 256 + t;
      int n = idx >> 7, tt = idx & 127;
      float acc = 0.f;
      for (int e = 0; e < 64; ++e) acc = fmaf(Wih_c[n * 64 + e], W2[e * 128 + tt], acc);
      Wfold_b[idx] = f2bf(acc);
    } else if (blk < 227) {               // gmask (64 blocks)
      int l = (blk - 163) * 4 + (t >> 6);
      int ln = t & 63;
      #pragma unroll
      for (int c = 0; c < 4; ++c) {
        int gv = Gmat[l * 256 + c * 64 + ln];
        unsigned long long msk = __ballot(gv > 0);
        if (ln == 0) {
          gmask[l * 8 + c * 2] = (unsigned)msk;
          gmask[l * 8 + c * 2 + 1] = (unsigned)(msk >> 32);
        }
      }
    } else if (blk < 251) {               // bf16 casts (24 blocks)
      int base = (blk - 227) * 2048;
      #pragma unroll
      for (int k = 0; k < 8; ++k) {
        int idx = base + k * 256 + t;
        if (idx < 16384) Whha_b[idx] = f2bf(Whh_a[idx]);
        else if (idx < 32768) Whhc_b[idx - 16384] = f2bf(Whh_c[idx - 16384]);
        else Wiha_b[idx - 32768] = f2bf(Wih_a[idx - 32768]);
      }
    }
  }
  grid.sync();

  // ---------------- Phase A: projections (2 jobs/block via half-block groups) ----------------
  {
    int group = tid >> 8, t = tid & 255;
    char* base = smem + group * 70144;
    float* x_raw = (float*)base;
    unsigned short* out_lds = (unsigned short*)base;            // [64][268]
    unsigned short* w_lds = (unsigned short*)(base + 34304);    // [256][68]
    float* bias_lds = (float*)(base + 69120);                   // [256]
    int job = blk * 2 + group;
    int row0 = job * 64;
    int lbA = row0 >> 8, m0 = row0 & 255;
    int lA = lbA >> 3, bA = lbA & 7;
    {
      const uint4* xs = (const uint4*)(x + ((bA * L_ + lA) * M_ + m0) * H_);
      uint4* xr = (uint4*)x_raw;
      #pragma unroll
      for (int k = 0; k < 4; ++k) {
        int i = k * 256 + t;
        if (i < 848) xr[i] = xs[i];
      }
    }
    #pragma unroll
    for (int k = 0; k < 8; ++k) {
      int i = k * 256 + t;
      int n = i >> 3, c8 = (i & 7) * 8;
      const unsigned short* src = n < 128 ? Wab_b + n * 64
                                : (n < 192 ? WQ_b + (n - 128) * 64 : WK_b + (n - 192) * 64);
      *(uint4*)&w_lds[n * 68 + c8] = *(const uint4*)(src + c8);
    }
    {
      float bv;
      if (t < 64) bv = ba[t];
      else if (t < 128) bv = bg[t - 64];
      else bv = bqk[t - 128];
      bias_lds[t] = bv;
    }
    __syncthreads();
    int lane = t & 63, w = t >> 6;
    int c16 = lane & 15, q4 = lane >> 4;
    int lrow = w * 16 + c16;
    bf16x8 a0, a1;
    #pragma unroll
    for (int e = 0; e < 8; ++e)
      a0[e] = (short)f2bf(x_raw[lrow * H_ + q4 * 8 + e]);
    #pragma unroll
    for (int e = 0; e < 8; ++e) {
      int c = 32 + q4 * 8 + e;
      a1[e] = (c < H_) ? (short)f2bf(x_raw[lrow * H_ + c]) : (short)0;
    }
    __syncthreads();
    #pragma unroll
    for (int nt = 0; nt < 16; ++nt) {
      bf16x8 b0 = *(const bf16x8*)&w_lds[(nt * 16 + c16) * 68 + q4 * 8];
      bf16x8 b1 = *(const bf16x8*)&w_lds[(nt * 16 + c16) * 68 + 32 + q4 * 8];
      float bs = bias_lds[nt * 16 + c16];
      f32x4 acc = {bs, bs, bs, bs};
      acc = __builtin_amdgcn_mfma_f32_16x16x32_bf16(a0, b0, acc, 0, 0, 0);
      acc = __builtin_amdgcn_mfma_f32_16x16x32_bf16(a1, b1, acc, 0, 0, 0);
      #pragma unroll
      for (int rr = 0; rr < 4; ++rr)
        out_lds[(w * 16 + q4 * 4 + rr) * 268 + nt * 16 + c16] = f2bf(acc[rr]);
    }
    __syncthreads();
    #pragma unroll
    for (int k = 0; k < 8; ++k) {
      int i = k * 256 + t;
      int r = i >> 5, seg = i & 31;
      int which = seg >> 3, n8 = (seg & 7) * 8;
      uint4 v = *(const uint4*)&out_lds[r * 268 + which * 64 + n8];
      unsigned short* dst = which == 0 ? a_lin_bf : which == 1 ? s_b : which == 2 ? q_b : k_b;
      *(uint4*)&dst[(row0 + r) * 64 + n8] = v;
    }
    #pragma unroll
    for (int k = 0; k < 4; ++k) {
      int i = k * 256 + t;
      int e = i >> 4, mc = i & 15;
      ushort4 v;
      v.x = out_lds[(mc * 4 + 0) * 268 + 64 + e];
      v.y = out_lds[(mc * 4 + 1) * 268 + 64 + e];
      v.z = out_lds[(mc * 4 + 2) * 268 + 64 + e];
      v.w = out_lds[(mc * 4 + 3) * 268 + 64 + e];
      *(ushort4*)&sT_b[(lbA * 64 + e) * 256 + m0 + mc * 4] = v;
    }
  }
  grid.sync();

  // ---------------- Phase B: attention (stage lb once, compute 2 quarters) ----------------
  {
    unsigned short* k_lds = (unsigned short*)smem;              // [256*68]
    unsigned short* sT_lds = (unsigned short*)(smem + 34816);   // [64*280]
    int lb = blk >> 1, half = blk & 1;
    int kbase = lb * 256;
    for (int i = tid; i < 2048; i += 512) {
      int s = i >> 3, e8 = (i & 7) * 8;
      *(uint4*)&k_lds[s * 68 + e8] = *(const uint4*)(k_b + (kbase + s) * 64 + e8);
    }
    for (int i = tid; i < 2048; i += 512) {
      int e = i >> 5, m8 = (i & 31) * 8;
      *(uint4*)&sT_lds[e * 280 + m8] = *(const uint4*)(sT_b + (lb * 64 + e) * 256 + m8);
    }
    __syncthreads();
    int lane = tid & 63, w = tid >> 6;
    int c16 = lane & 15, q4 = lane >> 4;
    int lrow0 = (w >> 1) * 16;
    int h0 = (w & 1) * 2;
    const bf16x8 z8 = {0, 0, 0, 0, 0, 0, 0, 0};
    #pragma unroll
    for (int q2 = 0; q2 < 2; ++q2) {
      int l0 = ((half << 1) | q2) << 6;
      int lrow = lb * 256 + l0 + lrow0;
      bf16x8 bq[2];
      #pragma unroll
      for (int hp = 0; hp < 2; ++hp) {
        int h = h0 + hp;
        bq[hp] = (q4 < 2) ? *(const bf16x8*)(q_b + (lrow + c16) * 64 + h * 16 + q4 * 8) : z8;
      }
      unsigned gwv[8];
      #pragma unroll
      for (int sp = 0; sp < 8; ++sp) gwv[sp] = gmask[(l0 + lrow0 + c16) * 8 + sp];
      f32x4 accO[2];
      float sumh[2];
      #pragma unroll
      for (int hp = 0; hp < 2; ++hp) { accO[hp] = (f32x4){0.f, 0.f, 0.f, 0.f}; sumh[hp] = 0.f; }
      #pragma unroll
      for (int sp = 0; sp < 8; ++sp) {
        unsigned gw = gwv[sp];
        #pragma unroll
        for (int hp = 0; hp < 2; ++hp) {
          int h = h0 + hp;
          unsigned pk0A, pk1A, pk0B, pk1B;
          #pragma unroll
          for (int tp = 0; tp < 2; ++tp) {
            int tt = sp * 2 + tp;
            bf16x8 ka = z8;
            if (q4 < 2) ka = *(const bf16x8*)&k_lds[(tt * 16 + c16) * 68 + h * 16 + q4 * 8];
            f32x4 d = __builtin_amdgcn_mfma_f32_16x16x32_bf16(ka, bq[hp], (f32x4){0.f, 0.f, 0.f, 0.f}, 0, 0, 0);
            int bitbase = tp * 16 + q4 * 4;
            float p0 = ((gw >> (bitbase + 0)) & 1u) ? __expf(d[0]) : 0.f;
            float p1 = ((gw >> (bitbase + 1)) & 1u) ? __expf(d[1]) : 0.f;
            float p2 = ((gw >> (bitbase + 2)) & 1u) ? __expf(d[2]) : 0.f;
            float p3 = ((gw >> (bitbase + 3)) & 1u) ? __expf(d[3]) : 0.f;
            sumh[hp] += (p0 + p1) + (p2 + p3);
            unsigned lo = (unsigned)f2bf(p0) | ((unsigned)f2bf(p1) << 16);
            unsigned hi = (unsigned)f2bf(p2) | ((unsigned)f2bf(p3) << 16);
            if (tp == 0) { pk0A = lo; pk1A = hi; } else { pk0B = lo; pk1B = hi; }
          }
          int srcA = ((q4 & 1) * 2) * 16 + c16, srcB = srcA + 16;
          unsigned g0A = (unsigned)__shfl((int)pk0A, srcA);
          unsigned g1A = (unsigned)__shfl((int)pk1A, srcA);
          unsigned g2A = (unsigned)__shfl((int)pk0A, srcB);
          unsigned g3A = (unsigned)__shfl((int)pk1A, srcB);
          unsigned g0B = (unsigned)__shfl((int)pk0B, srcA);
          unsigned g1B = (unsigned)__shfl((int)pk1B, srcA);
          unsigned g2B = (unsigned)__shfl((int)pk0B, srcB);
          unsigned g3B = (unsigned)__shfl((int)pk1B, srcB);
          bool useB = (q4 >= 2);
          uint4 av;
          av.x = useB ? g0B : g0A;
          av.y = useB ? g1B : g1A;
          av.z = useB ? g2B : g2A;
          av.w = useB ? g3B : g3A;
          bf16x8 af = __builtin_bit_cast(bf16x8, av);
          bf16x8 bs = *(const bf16x8*)&sT_lds[(h * 16 + c16) * 280 + sp * 32 + q4 * 8];
          accO[hp] = __builtin_amdgcn_mfma_f32_16x16x32_bf16(af, bs, accO[hp], 0, 0, 0);
        }
      }
      #pragma unroll
      for (int hp = 0; hp < 2; ++hp) {
        int h = h0 + hp;
        float s = sumh[hp];
        s += __shfl_xor(s, 16);
        s += __shfl_xor(s, 32);
        #pragma unroll
        for (int r = 0; r < 4; ++r) {
          float sv = __shfl(s, q4 * 4 + r);
          float o = accO[hp][r] / sv;
          so_b[(lb * 256 + l0 + lrow0 + q4 * 4 + r) * 64 + h * 16 + c16] = f2bf(o);
        }
      }
    }
  }
  grid.sync();

  // ---------------- Phase R: LSTM recurrence + heads (20 barriers both paths) ----------------
  if (tid < 256) {
    int t = tid;
    unsigned short (*h_lds)[16][72] = (unsigned short(*)[16][72])(smem);          // [2][16][72]
    unsigned short (*ha_lds)[72] = (unsigned short(*)[72])(smem + 4608);          // [16][72]
    float (*logit_lds)[16] = (float(*)[16])(smem + 6912);
    float (*grp_lds)[8] = (float(*)[8])(smem + 7936);
    float (*val_lds)[4] = (float(*)[4])(smem + 8448);
    int which = blk >> 7, g = blk & 127;
    int seq0 = g * 16;
    int b = seq0 >> 8, m0 = seq0 & 255;
    int lane = t & 63, w = t >> 6;
    int c16 = lane & 15, q4 = lane >> 4;
    int hs0 = w * 16;
    const unsigned short* Whh_bp = which ? Whhc_b : Whha_b;
    const float* bih = which ? bih_c : bih_a;
    const float* bhh = which ? bhh_c : bhh_a;
    bf16x8 bwhh[4][2];
    float bias[4];
    #pragma unroll
    for (int nt = 0; nt < 4; ++nt) {
      int n = nt * 64 + hs0 + c16;
      bias[nt] = bih[n] + bhh[n] + (which ? bias_fold[n] : 0.f);
      #pragma unroll
      for (int kf = 0; kf < 2; ++kf)
        bwhh[nt][kf] = *(const bf16x8*)(Whh_bp + n * 64 + kf * 32 + q4 * 8);
    }
    for (int i = t; i < 576; i += 256) ((unsigned*)smem)[i] = 0u;
    float cr[4] = {0.f, 0.f, 0.f, 0.f};
    float hv[4] = {0.f, 0.f, 0.f, 0.f};
    const int STEP = 2048 * 64;
    __syncthreads();                                   // #1
    int cur = 0;
    if (which == 0) {
      bf16x8 bwin[4][2];
      #pragma unroll
      for (int nt = 0; nt < 4; ++nt) {
        int n = nt * 64 + hs0 + c16;
        #pragma unroll
        for (int kf = 0; kf < 2; ++kf)
          bwin[nt][kf] = *(const bf16x8*)(Wiha_b + n * 64 + kf * 32 + q4 * 8);
      }
      const unsigned short* inb = a_lin_bf + (b * 256 + m0 + c16) * 64;
      bf16x8 i0c = *(const bf16x8*)(inb + q4 * 8);
      bf16x8 i1c = *(const bf16x8*)(inb + 32 + q4 * 8);
      for (int l = 0; l < L_; ++l) {
        bf16x8 i0n = i0c, i1n = i1c;
        if (l < L_ - 1) {
          i0n = *(const bf16x8*)(inb + (l + 1) * STEP + q4 * 8);
          i1n = *(const bf16x8*)(inb + (l + 1) * STEP + 32 + q4 * 8);
        }
        bf16x8 ah0 = *(const bf16x8*)&h_lds[cur][c16][q4 * 8];
        bf16x8 ah1 = *(const bf16x8*)&h_lds[cur][c16][32 + q4 * 8];
        f32x4 acc[4];
        #pragma unroll
        for (int nt = 0; nt < 4; ++nt) {
          f32x4 a = {bias[nt], bias[nt], bias[nt], bias[nt]};
          a = __builtin_amdgcn_mfma_f32_16x16x32_bf16(i0c, bwin[nt][0], a, 0, 0, 0);
          a = __builtin_amdgcn_mfma_f32_16x16x32_bf16(i1c, bwin[nt][1], a, 0, 0, 0);
          a = __builtin_amdgcn_mfma_f32_16x16x32_bf16(ah0, bwhh[nt][0], a, 0, 0, 0);
          a = __builtin_amdgcn_mfma_f32_16x16x32_bf16(ah1, bwhh[nt][1], a, 0, 0, 0);
          acc[nt] = a;
        }
        #pragma unroll
        for (int rr = 0; rr < 4; ++rr) {
          float si = sigm(acc[0][rr]);
          float sf = sigm(acc[1][rr]);
          float gg = ftanh(acc[2][rr]);
          float so_ = sigm(acc[3][rr]);
          cr[rr] = sf * cr[rr] + si * gg;
          hv[rr] = so_ * ftanh(cr[rr]);
          h_lds[cur ^ 1][q4 * 4 + rr][hs0 + c16] = f2bf(hv[rr]);
        }
        __syncthreads();                               // #2..#17
        cur ^= 1;
        i0c = i0n; i1c = i1n;
      }
    } else {
      bf16x8 bwf[4][4];
      #pragma unroll
      for (int nt = 0; nt < 4; ++nt) {
        int n = nt * 64 + hs0 + c16;
        #pragma unroll
        for (int kc = 0; kc < 4; ++kc)
          bwf[nt][kc] = *(const bf16x8*)(Wfold_b + n * 128 + kc * 32 + q4 * 8);
      }
      const unsigned short* sbB = s_b + (b * 256 + m0 + c16) * 64;
      const unsigned short* soB = so_b + (b * 256 + m0 + c16) * 64;
      bf16x8 s0c = *(const bf16x8*)(sbB + q4 * 8);
      bf16x8 s1c = *(const bf16x8*)(sbB + 32 + q4 * 8);
      bf16x8 o0c = *(const bf16x8*)(soB + q4 * 8);
      bf16x8 o1c = *(const bf16x8*)(soB + 32 + q4 * 8);
      for (int l = 0; l < L_; ++l) {
        bf16x8 s0n = s0c, s1n = s1c, o0n = o0c, o1n = o1c;
        if (l < L_ - 1) {
          s0n = *(const bf16x8*)(sbB + (l + 1) * STEP + q4 * 8);
          s1n = *(const bf16x8*)(sbB + (l + 1) * STEP + 32 + q4 * 8);
          o0n = *(const bf16x8*)(soB + (l + 1) * STEP + q4 * 8);
          o1n = *(const bf16x8*)(soB + (l + 1) * STEP + 32 + q4 * 8);
        }
        bf16x8 ah0 = *(const bf16x8*)&h_lds[cur][c16][q4 * 8];
        bf16x8 ah1 = *(const bf16x8*)&h_lds[cur][c16][32 + q4 * 8];
        f32x4 acc[4];
        #pragma unroll
        for (int nt = 0; nt < 4; ++nt) {
          f32x4 a = {bias[nt], bias[nt], bias[nt], bias[nt]};
          a = __builtin_amdgcn_mfma_f32_16x16x32_bf16(s0c, bwf[nt][0], a, 0, 0, 0);
          a = __builtin_amdgcn_mfma_f32_16x16x32_bf16(s1c, bwf[nt][1], a, 0, 0, 0);
          a = __builtin_amdgcn_mfma_f32_16x16x32_bf16(o0c, bwf[nt][2], a, 0, 0, 0);
          a = __builtin_amdgcn_mfma_f32_16x16x32_bf16(o1c, bwf[nt][3], a, 0, 0, 0);
          a = __builtin_amdgcn_mfma_f32_16x16x32_bf16(ah0, bwhh[nt][0], a, 0, 0, 0);
          a = __builtin_amdgcn_mfma_f32_16x16x32_bf16(ah1, bwhh[nt][1], a, 0, 0, 0);
          acc[nt] = a;
        }
        #pragma unroll
        for (int rr = 0; rr < 4; ++rr) {
          float si = sigm(acc[0][rr]);
          float sf = sigm(acc[1][rr]);
          float gg = ftanh(acc[2][rr]);
          float so_ = sigm(acc[3][rr]);
          cr[rr] = sf * cr[rr] + si * gg;
          hv[rr] = so_ * ftanh(cr[rr]);
          h_lds[cur ^ 1][q4 * 4 + rr][hs0 + c16] = f2bf(hv[rr]);
        }
        __syncthreads();                               // #2..#17
        cur ^= 1;
        s0c = s0n; s1c = s1n; o0c = o0n; o1c = o1n;
      }
    }
    bf16x8 fh0 = *(const bf16x8*)&h_lds[cur][c16][q4 * 8];
    bf16x8 fh1 = *(const bf16x8*)&h_lds[cur][c16][32 + q4 * 8];
    if (which == 0) {
      bf16x8 bm1[2];
      #pragma unroll
      for (int kf = 0; kf < 2; ++kf) {
        const float* wp = Wma1 + (hs0 + c16) * 64 + kf * 32 + q4 * 8;
        bf16x8 bb;
        #pragma unroll
        for (int j = 0; j < 8; ++j) bb[j] = (short)f2bf(wp[j]);
        bm1[kf] = bb;
      }
      float bs = bma1[hs0 + c16];
      f32x4 acc = {bs, bs, bs, bs};
      acc = __builtin_amdgcn_mfma_f32_16x16x32_bf16(fh0, bm1[0], acc, 0, 0, 0);
      acc = __builtin_amdgcn_mfma_f32_16x16x32_bf16(fh1, bm1[1], acc, 0, 0, 0);
      #pragma unroll
      for (int rr = 0; rr < 4; ++rr)
        ha_lds[q4 * 4 + rr][hs0 + c16] = f2bf(ftanh(acc[rr]));
      __syncthreads();                                 // #18
      if (w == 0) {
        bf16x8 af0 = *(const bf16x8*)&ha_lds[c16][q4 * 8];
        bf16x8 af1 = *(const bf16x8*)&ha_lds[c16][32 + q4 * 8];
        const bf16x8 z8 = {0, 0, 0, 0, 0, 0, 0, 0};
        bf16x8 bw2[2] = {z8, z8};
        float bs2 = 0.f;
        if (c16 < 15) {
          #pragma unroll
          for (int kf = 0; kf < 2; ++kf) {
            const float* wp = Wma2 + c16 * 64 + kf * 32 + q4 * 8;
            bf16x8 bb;
            #pragma unroll
            for (int j = 0; j < 8; ++j) bb[j] = (short)f2bf(wp[j]);
            bw2[kf] = bb;
          }
          bs2 = bma2[c16];
        }
        f32x4 acc2 = {bs2, bs2, bs2, bs2};
        acc2 = __builtin_amdgcn_mfma_f32_16x16x32_bf16(af0, bw2[0], acc2, 0, 0, 0);
        acc2 = __builtin_amdgcn_mfma_f32_16x16x32_bf16(af1, bw2[1], acc2, 0, 0, 0);
        #pragma unroll
        for (int rr = 0; rr < 4; ++rr)
          logit_lds[q4 * 4 + rr][c16] = acc2[rr];
      }
      __syncthreads();                                 // #19
      if (t < 48) {
        int useq = t & 15, tt = t >> 4;
        int n = seq0 + useq;
        float l0 = logit_lds[useq][tt * 5 + 0], l1 = logit_lds[useq][tt * 5 + 1];
        float l2 = logit_lds[useq][tt * 5 + 2], l3 = logit_lds[useq][tt * 5 + 3];
        float l4 = logit_lds[useq][tt * 5 + 4];
        float mx = fmaxf(fmaxf(fmaxf(l0, l1), fmaxf(l2, l3)), l4);
        float sm = __expf(l0 - mx) + __expf(l1 - mx) + __expf(l2 - mx) +
                   __expf(l3 - mx) + __expf(l4 - mx);
        float lse = __logf(sm) + mx;
        int a = action[n * 3 + tt];
        float lp0 = l0 - lse, lp1 = l1 - lse, lp2 = l2 - lse, lp3 = l3 - lse, lp4 = l4 - lse;
        float lpsel = logit_lds[useq][tt * 5 + a] - lse;
        float ent = -(__expf(lp0) * lp0 + __expf(lp1) * lp1 + __expf(lp2) * lp2 +
                      __expf(lp3) * lp3 + __expf(lp4) * lp4);
        grp_lds[useq][tt] = lpsel;
        grp_lds[useq][4 + tt] = ent;
        out[n * 3 + tt] = (float)a;
      }
      __syncthreads();                                 // #20
      if (t < 16) {
        int n = seq0 + t;
        out[6144 + n] = grp_lds[t][0] + grp_lds[t][1] + grp_lds[t][2];
        out[8192 + n] = grp_lds[t][4] + grp_lds[t][5] + grp_lds[t][6];
      }
    } else {
      bf16x8 bm1[2];
      #pragma unroll
      for (int kf = 0; kf < 2; ++kf) {
        const float* wp = Wmc1 + (hs0 + c16) * 64 + kf * 32 + q4 * 8;
        bf16x8 bb;
        #pragma unroll
        for (int j = 0; j < 8; ++j) bb[j] = (short)f2bf(wp[j]);
        bm1[kf] = bb;
      }
      float bs = bmc1[hs0 + c16];
      f32x4 acc = {bs, bs, bs, bs};
      acc = __builtin_amdgcn_mfma_f32_16x16x32_bf16(fh0, bm1[0], acc, 0, 0, 0);
      acc = __builtin_amdgcn_mfma_f32_16x16x32_bf16(fh1, bm1[1], acc, 0, 0, 0);
      float wv2 = Wmc2[hs0 + c16];
      float pv[4];
      #pragma unroll
      for (int rr = 0; rr < 4; ++rr) pv[rr] = ftanh(acc[rr]) * wv2;
      #pragma unroll
      for (int rr = 0; rr < 4; ++rr) {
        pv[rr] += __shfl_xor(pv[rr], 1);
        pv[rr] += __shfl_xor(pv[rr], 2);
        pv[rr] += __shfl_xor(pv[rr], 4);
        pv[rr] += __shfl_xor(pv[rr], 8);
      }
      if (c16 == 0) {
        #pragma unroll
        for (int rr = 0; rr < 4; ++rr) val_lds[q4 * 4 + rr][w] = pv[rr];
      }
      __syncthreads();                                 // #18
      if (t < 16) {
        int n = seq0 + t;
        out[10240 + n] = val_lds[t][0] + val_lds[t][1] + val_lds[t][2] +
                         val_lds[t][3] + bmc2[0];
      }
      __syncthreads();                                 // #19 pad
      __syncthreads();                                 // #20 pad
    }
  } else {
    for (int i = 0; i < 20; ++i) __syncthreads();
  }
}

// ================= Legacy 4-kernel fallback (round-11, verified) =================
__global__ __launch_bounds__(256) void kP_pre(
    const float* __restrict__ Wa, const float* __restrict__ Wg,
    const float* __restrict__ bg,
    const float* __restrict__ Qw, const float* __restrict__ Kw,
    unsigned short* __restrict__ WQ_b, unsigned short* __restrict__ WK_b,
    float* __restrict__ bqk, unsigned short* __restrict__ Wab_b) {
  int blk = blockIdx.x, tid = threadIdx.x;
  if (blk < 32) {
    int idx = blk * 256 + tid;
    int which = idx >> 12, n = (idx >> 6) & 63, j = idx & 63;
    const float* Mm = which ? Kw : Qw;
    float acc = 0.f;
    if (j < 53) {
      for (int e = 0; e < 64; ++e) acc = fmaf(Mm[e * 64 + n], Wg[e * 53 + j], acc);
      if (which == 0) acc *= SCALE_;
    }
    (which ? WK_b : WQ_b)[n * 64 + j] = f2bf(acc);
  } else if (blk == 32) {
    if (tid < 128) {
      int which = tid >> 6, n = tid & 63;
      const float* Mm = which ? Kw : Qw;
      float acc = 0.f;
      for (int e = 0; e < 64; ++e) acc = fmaf(bg[e], Mm[e * 64 + n], acc);
      if (which == 0) acc *= SCALE_;
      bqk[tid] = acc;
    }
  } else {
    int base = (blk - 33) * 4096;
    #pragma unroll
    for (int k = 0; k < 16; ++k) {
      int idx = base + k * 256 + tid;
      int n = idx >> 6, j = idx & 63;
      float v = 0.f;
      if (j < 53) v = (n < 64) ? Wa[n * 53 + j] : Wg[(n - 64) * 53 + j];
      Wab_b[idx] = f2bf(v);
    }
  }
}

__global__ __launch_bounds__(256, 2) void kA_lin(const float* __restrict__ x,
    const unsigned short* __restrict__ Wab_b,
    const unsigned short* __restrict__ WQ_b, const unsigned short* __restrict__ WK_b,
    const float* __restrict__ ba, const float* __restrict__ bg,
    const float* __restrict__ bqk,
    const int* __restrict__ Gmat, const float* __restrict__ Wih_c,
    const float* __restrict__ W2, const float* __restrict__ b2,
    const float* __restrict__ Whh_a, const float* __restrict__ Whh_c,
    const float* __restrict__ Wih_a,
    unsigned short* __restrict__ a_lin_bf, unsigned short* __restrict__ s_b,
    unsigned short* __restrict__ q_b, unsigned short* __restrict__ k_b,
    unsigned short* __restrict__ sT_b,
    unsigned short* __restrict__ Wfold_b, float* __restrict__ bias_fold,
    unsigned* __restrict__ gmask,
    unsigned short* __restrict__ Whha_b, unsigned short* __restrict__ Whhc_b,
    unsigned short* __restrict__ Wiha_b) {
  int tid = threadIdx.x, blk = blockIdx.x;
  if (blk >= 512) {
    int b2k = blk - 512;
    if (b2k < 128) {
      int idx = b2k * 256 + tid;
      int n = idx >> 7, t = idx & 127;
      float acc = 0.f;
      for (int e = 0; e < 64; ++e) acc = fmaf(Wih_c[n * 64 + e], W2[e * 128 + t], acc);
      Wfold_b[idx] = f2bf(acc);
    } else if (b2k < 192) {
      int l = (b2k - 128) * 4 + (tid >> 6);
      int ln = tid & 63;
      #pragma unroll
      for (int c = 0; c < 4; ++c) {
        int gv = Gmat[l * 256 + c * 64 + ln];
        unsigned long long msk = __ballot(gv > 0);
        if (ln == 0) {
          gmask[l * 8 + c * 2] = (unsigned)msk;
          gmask[l * 8 + c * 2 + 1] = (unsigned)(msk >> 32);
        }
      }
    } else if (b2k == 192) {
      float acc = 0.f;
      for (int e = 0; e < 64; ++e) acc = fmaf(Wih_c[tid * 64 + e], b2[e], acc);
      bias_fold[tid] = acc;
    } else {
      int base = (b2k - 193) * 2048;
      #pragma unroll
      for (int k = 0; k < 8; ++k) {
        int idx = base + k * 256 + tid;
        if (idx < 16384) Whha_b[idx] = f2bf(Whh_a[idx]);
        else if (idx < 32768) Whhc_b[idx - 16384] = f2bf(Whh_c[idx - 16384]);
        else Wiha_b[idx - 32768] = f2bf(Wih_a[idx - 32768]);
      }
    }
    return;
  }
  __shared__ __attribute__((aligned(16))) char smem[70144];
  float* x_raw = (float*)smem;
  unsigned short* out_lds = (unsigned short*)smem;
  unsigned short* w_lds = (unsigned short*)(smem + 34304);
  float* bias_lds = (float*)(smem + 69120);
  int row0 = blk * 64;
  int lbA = row0 >> 8, m0 = row0 & 255;
  int lA = lbA >> 3, bA = lbA & 7;
  {
    const uint4* xs = (const uint4*)(x + ((bA * L_ + lA) * M_ + m0) * H_);
    uint4* xr = (uint4*)x_raw;
    #pragma unroll
    for (int k = 0; k < 4; ++k) {
      int i = k * 256 + tid;
      if (i < 848) xr[i] = xs[i];
    }
  }
  #pragma unroll
  for (int k = 0; k < 8; ++k) {
    int i = k * 256 + tid;
    int n = i >> 3, c8 = (i & 7) * 8;
    const unsigned short* src = n < 128 ? Wab_b + n * 64
                              : (n < 192 ? WQ_b + (n - 128) * 64 : WK_b + (n - 192) * 64);
    *(uint4*)&w_lds[n * 68 + c8] = *(const uint4*)(src + c8);
  }
  {
    float bv;
    if (tid < 64) bv = ba[tid];
    else if (tid < 128) bv = bg[tid - 64];
    else bv = bqk[tid - 128];
    bias_lds[tid] = bv;
  }
  __syncthreads();
  int lane = tid & 63, w = tid >> 6;
  int c16 = lane & 15, q4 = lane >> 4;
  int lrow = w * 16 + c16;
  bf16x8 a0, a1;
  #pragma unroll
  for (int e = 0; e < 8; ++e)
    a0[e] = (short)f2bf(x_raw[lrow * H_ + q4 * 8 + e]);
  #pragma unroll
  for (int e = 0; e < 8; ++e) {
    int c = 32 + q4 * 8 + e;
    a1[e] = (c < H_) ? (short)f2bf(x_raw[lrow * H_ + c]) : (short)0;
  }
  __syncthreads();
  #pragma unroll
  for (int nt = 0; nt < 16; ++nt) {
    bf16x8 b0 = *(const bf16x8*)&w_lds[(nt * 16 + c16) * 68 + q4 * 8];
    bf16x8 b1 = *(const bf16x8*)&w_lds[(nt * 16 + c16) * 68 + 32 + q4 * 8];
    float bs = bias_lds[nt * 16 + c16];
    f32x4 acc = {bs, bs, bs, bs};
    acc = __builtin_amdgcn_mfma_f32_16x16x32_bf16(a0, b0, acc, 0, 0, 0);
    acc = __builtin_amdgcn_mfma_f32_16x16x32_bf16(a1, b1, acc, 0, 0, 0);
    #pragma unroll
    for (int rr = 0; rr < 4; ++rr)
      out_lds[(w * 16 + q4 * 4 + rr) * 268 + nt * 16 + c16] = f2bf(acc[rr]);
  }
  __syncthreads();
  #pragma unroll
  for (int k = 0; k < 8; ++k) {
    int i = k * 256 + tid;
    int r = i >> 5, seg = i & 31;
    int which = seg >> 3, n8 = (seg & 7) * 8;
    uint4 v = *(const uint4*)&out_lds[r * 268 + which * 64 + n8];
    unsigned short* dst = which == 0 ? a_lin_bf : which == 1 ? s_b : which == 2 ? q_b : k_b;
    *(uint4*)&dst[(row0 + r) * 64 + n8] = v;
  }
  #pragma unroll
  for (int k = 0; k < 4; ++k) {
    int i = k * 256 + tid;
    int e = i >> 4, mc = i & 15;
    ushort4 v;
    v.x = out_lds[(mc * 4 + 0) * 268 + 64 + e];
    v.y = out_lds[(mc * 4 + 1) * 268 + 64 + e];
    v.z = out_lds[(mc * 4 + 2) * 268 + 64 + e];
    v.w = out_lds[(mc * 4 + 3) * 268 + 64 + e];
    *(ushort4*)&sT_b[(lbA * 64 + e) * 256 + m0 + mc * 4] = v;
  }
}

__global__ __launch_bounds__(512, 4) void kB_attn(
    const unsigned short* __restrict__ qb, const unsigned short* __restrict__ kb,
    const unsigned short* __restrict__ sT, const unsigned* __restrict__ gmask,
    unsigned short* __restrict__ so_b) {
  __shared__ __attribute__((aligned(16))) unsigned short k_lds[256 * 68];
  __shared__ __attribute__((aligned(16))) unsigned short sT_lds[64 * 280];
  int bid = blockIdx.x;
  int xcd = bid & 7;
  int rest = bid >> 3;
  int l0 = (rest & 3) << 6;
  int lb = (rest >> 2) * 8 + xcd;
  int tid = threadIdx.x;
  int kbase = lb * 256;
  for (int i = tid; i < 2048; i += 512) {
    int s = i >> 3, e8 = (i & 7) * 8;
    *(uint4*)&k_lds[s * 68 + e8] = *(const uint4*)(kb + (kbase + s) * 64 + e8);
  }
  for (int i = tid; i < 2048; i += 512) {
    int e = i >> 5, m8 = (i & 31) * 8;
    *(uint4*)&sT_lds[e * 280 + m8] = *(const uint4*)(sT + (lb * 64 + e) * 256 + m8);
  }
  int lane = tid & 63, w = tid >> 6;
  int c16 = lane & 15, q4 = lane >> 4;
  int lrow0 = (w >> 1) * 16;
  int h0 = (w & 1) * 2;
  int lrow = lb * 256 + l0 + lrow0;
  const bf16x8 z8 = {0, 0, 0, 0, 0, 0, 0, 0};
  bf16x8 bq[2];
  #pragma unroll
  for (int hp = 0; hp < 2; ++hp) {
    int h = h0 + hp;
    bq[hp] = (q4 < 2) ? *(const bf16x8*)(qb + (lrow + c16) * 64 + h * 16 + q4 * 8) : z8;
  }
  unsigned gwv[8];
  #pragma unroll
  for (int sp = 0; sp < 8; ++sp) gwv[sp] = gmask[(l0 + lrow0 + c16) * 8 + sp];
  __syncthreads();
  f32x4 accO[2];
  float sumh[2];
  #pragma unroll
  for (int hp = 0; hp < 2; ++hp) { accO[hp] = (f32x4){0.f, 0.f, 0.f, 0.f}; sumh[hp] = 0.f; }
  #pragma unroll
  for (int sp = 0; sp < 8; ++sp) {
    unsigned gw = gwv[sp];
    #pragma unroll
    for (int hp = 0; hp < 2; ++hp) {
      int h = h0 + hp;
      unsigned pk0A, pk1A, pk0B, pk1B;
      #pragma unroll
      for (int tp = 0; tp < 2; ++tp) {
        int t = sp * 2 + tp;
        bf16x8 ka = z8;
        if (q4 < 2) ka = *(const bf16x8*)&k_lds[(t * 16 + c16) * 68 + h * 16 + q4 * 8];
        f32x4 d = __builtin_amdgcn_mfma_f32_16x16x32_bf16(ka, bq[hp], (f32x4){0.f, 0.f, 0.f, 0.f}, 0, 0, 0);
        int bitbase = tp * 16 + q4 * 4;
        float p0 = ((gw >> (bitbase + 0)) & 1u) ? __expf(d[0]) : 0.f;
        float p1 = ((gw >> (bitbase + 1)) & 1u) ? __expf(d[1]) : 0.f;
        float p2 = ((gw >> (bitbase + 2)) & 1u) ? __expf(d[2]) : 0.f;
        float p3 = ((gw >> (bitbase + 3)) & 1u) ? __expf(d[3]) : 0.f;
        sumh[hp] += (p0 + p1) + (p2 + p3);
        unsigned lo = (unsigned)f2bf(p0) | ((unsigned)f2bf(p1) << 16);
        unsigned hi = (unsigned)f2bf(p2) | ((unsigned)f2bf(p3) << 16);
        if (tp == 0) { pk0A = lo; pk1A = hi; } else { pk0B = lo; pk1B = hi; }
      }
      int srcA = ((q4 & 1) * 2) * 16 + c16, srcB = srcA + 16;
      unsigned g0A = (unsigned)__shfl((int)pk0A, srcA);
      unsigned g1A = (unsigned)__shfl((int)pk1A, srcA);
      unsigned g2A = (unsigned)__shfl((int)pk0A, srcB);
      unsigned g3A = (unsigned)__shfl((int)pk1A, srcB);
      unsigned g0B = (unsigned)__shfl((int)pk0B, srcA);
      unsigned g1B = (unsigned)__shfl((int)pk1B, srcA);
      unsigned g2B = (unsigned)__shfl((int)pk0B, srcB);
      unsigned g3B = (unsigned)__shfl((int)pk1B, srcB);
      bool useB = (q4 >= 2);
      uint4 av;
      av.x = useB ? g0B : g0A;
      av.y = useB ? g1B : g1A;
      av.z = useB ? g2B : g2A;
      av.w = useB ? g3B : g3A;
      bf16x8 af = __builtin_bit_cast(bf16x8, av);
      bf16x8 bs = *(const bf16x8*)&sT_lds[(h * 16 + c16) * 280 + sp * 32 + q4 * 8];
      accO[hp] = __builtin_amdgcn_mfma_f32_16x16x32_bf16(af, bs, accO[hp], 0, 0, 0);
    }
  }
  #pragma unroll
  for (int hp = 0; hp < 2; ++hp) {
    int h = h0 + hp;
    float s = sumh[hp];
    s += __shfl_xor(s, 16);
    s += __shfl_xor(s, 32);
    #pragma unroll
    for (int r = 0; r < 4; ++r) {
      float sv = __shfl(s, q4 * 4 + r);
      float o = accO[hp][r] / sv;
      so_b[(lb * 256 + l0 + lrow0 + q4 * 4 + r) * 64 + h * 16 + c16] = f2bf(o);
    }
  }
}

__global__ __launch_bounds__(256, 1) void kR_lstm(
    const unsigned short* __restrict__ a_lin_bf,
    const unsigned short* __restrict__ s_b, const unsigned short* __restrict__ so_b,
    const unsigned short* __restrict__ Wfold_b, const float* __restrict__ bias_fold,
    const unsigned short* __restrict__ Wiha_b,
    const unsigned short* __restrict__ Whha_b, const unsigned short* __restrict__ Whhc_b,
    const float* __restrict__ bih_a, const float* __restrict__ bhh_a,
    const float* __restrict__ bih_c, const float* __restrict__ bhh_c,
    const int* __restrict__ action,
    const float* __restrict__ Wma1, const float* __restrict__ bma1,
    const float* __restrict__ Wma2, const float* __restrict__ bma2,
    const float* __restrict__ Wmc1, const float* __restrict__ bmc1,
    const float* __restrict__ Wmc2, const float* __restrict__ bmc2,
    float* __restrict__ out) {
  int blk = blockIdx.x;
  int which = blk >> 7, g = blk & 127;
  int seq0 = g * 16;
  int b = seq0 >> 8, m0 = seq0 & 255;
  __shared__ __attribute__((aligned(16))) unsigned short h_lds[2][16][72];
  __shared__ __attribute__((aligned(16))) unsigned short ha_lds[16][72];
  __shared__ float logit_lds[16][16];
  __shared__ float grp_lds[16][8];
  __shared__ float val_lds[16][4];
  int tid = threadIdx.x;
  int lane = tid & 63, w = tid >> 6;
  int c16 = lane & 15, q4 = lane >> 4;
  int hs0 = w * 16;
  const unsigned short* Whh_b = which ? Whhc_b : Whha_b;
  const float* bih = which ? bih_c : bih_a;
  const float* bhh = which ? bhh_c : bhh_a;
  bf16x8 bwhh[4][2];
  float bias[4];
  #pragma unroll
  for (int nt = 0; nt < 4; ++nt) {
    int n = nt * 64 + hs0 + c16;
    bias[nt] = bih[n] + bhh[n] + (which ? bias_fold[n] : 0.f);
    #pragma unroll
    for (int kf = 0; kf < 2; ++kf)
      bwhh[nt][kf] = *(const bf16x8*)(Whh_b + n * 64 + kf * 32 + q4 * 8);
  }
  for (int i = tid; i < 576; i += 256) ((unsigned*)h_lds)[i] = 0u;
  float cr[4] = {0.f, 0.f, 0.f, 0.f};
  const int STEP = 2048 * 64;
  __syncthreads();
  int cur = 0;
  if (which == 0) {
    bf16x8 bwin[4][2];
    #pragma unroll
    for (int nt = 0; nt < 4; ++nt) {
      int n = nt * 64 + hs0 + c16;
      #pragma unroll
      for (int kf = 0; kf < 2; ++kf)
        bwin[nt][kf] = *(const bf16x8*)(Wiha_b + n * 64 + kf * 32 + q4 * 8);
    }
    const unsigned short* inb = a_lin_bf + (b * 256 + m0 + c16) * 64;
    bf16x8 i0c = *(const bf16x8*)(inb + q4 * 8);
    bf16x8 i1c = *(const bf16x8*)(inb + 32 + q4 * 8);
    for (int l = 0; l < L_; ++l) {
      bf16x8 i0n = i0c, i1n = i1c;
      if (l < L_ - 1) {
        i0n = *(const bf16x8*)(inb + (l + 1) * STEP + q4 * 8);
        i1n = *(const bf16x8*)(inb + (l + 1) * STEP + 32 + q4 * 8);
      }
      bf16x8 ah0 = *(const bf16x8*)&h_lds[cur][c16][q4 * 8];
      bf16x8 ah1 = *(const bf16x8*)&h_lds[cur][c16][32 + q4 * 8];
      f32x4 acc[4];
      #pragma unroll
      for (int nt = 0; nt < 4; ++nt) {
        f32x4 a = {bias[nt], bias[nt], bias[nt], bias[nt]};
        a = __builtin_amdgcn_mfma_f32_16x16x32_bf16(i0c, bwin[nt][0], a, 0, 0, 0);
        a = __builtin_amdgcn_mfma_f32_16x16x32_bf16(i1c, bwin[nt][1], a, 0, 0, 0);
        a = __builtin_amdgcn_mfma_f32_16x16x32_bf16(ah0, bwhh[nt][0], a, 0, 0, 0);
        a = __builtin_amdgcn_mfma_f32_16x16x32_bf16(ah1, bwhh[nt][1], a, 0, 0, 0);
        acc[nt] = a;
      }
      #pragma unroll
      for (int rr = 0; rr < 4; ++rr) {
        float si = sigm(acc[0][rr]);
        float sf = sigm(acc[1][rr]);
        float gg = ftanh(acc[2][rr]);
        float so_ = sigm(acc[3][rr]);
        cr[rr] = sf * cr[rr] + si * gg;
        float hvv = so_ * ftanh(cr[rr]);
        h_lds[cur ^ 1][q4 * 4 + rr][hs0 + c16] = f2bf(hvv);
      }
      __syncthreads();
      cur ^= 1;
      i0c = i0n; i1c = i1n;
    }
  } else {
    bf16x8 bwf[4][4];
    #pragma unroll
    for (int nt = 0; nt < 4; ++nt) {
      int n = nt * 64 + hs0 + c16;
      #pragma unroll
      for (int kc = 0; kc < 4; ++kc)
        bwf[nt][kc] = *(const bf16x8*)(Wfold_b + n * 128 + kc * 32 + q4 * 8);
    }
    const unsigned short* sbB = s_b + (b * 256 + m0 + c16) * 64;
    const unsigned short* soB = so_b + (b * 256 + m0 + c16) * 64;
    bf16x8 s0c = *(const bf16x8*)(sbB + q4 * 8);
    bf16x8 s1c = *(const bf16x8*)(sbB + 32 + q4 * 8);
    bf16x8 o0c = *(const bf16x8*)(soB + q4 * 8);
    bf16x8 o1c = *(const bf16x8*)(soB + 32 + q4 * 8);
    for (int l = 0; l < L_; ++l) {
      bf16x8 s0n = s0c, s1n = s1c, o0n = o0c, o1n = o1c;
      if (l < L_ - 1) {
        s0n = *(const bf16x8*)(sbB + (l + 1) * STEP + q4 * 8);
        s1n = *(const bf16x8*)(sbB + (l + 1) * STEP + 32 + q4 * 8);
        o0n = *(const bf16x8*)(soB + (l + 1) * STEP + q4 * 8);
        o1n = *(const bf16x8*)(soB + (l + 1) * STEP + 32 + q4 * 8);
      }
      bf16x8 ah0 = *(const bf16x8*)&h_lds[cur][c16][q4 * 8];
      bf16x8 ah1 = *(const bf16x8*)&h_lds[cur][c16][32 + q4 * 8];
      f32x4 acc[4];
      #pragma unroll
      for (int nt = 0; nt < 4; ++nt) {
        f32x4 a = {bias[nt], bias[nt], bias[nt], bias[nt]};
        a = __builtin_amdgcn_mfma_f32_16x16x32_bf16(s0c, bwf[nt][0], a, 0, 0, 0);
        a = __builtin_amdgcn_mfma_f32_16x16x32_bf16(s1c, bwf[nt][1], a, 0, 0, 0);
        a = __builtin_amdgcn_mfma_f32_16x16x32_bf16(o0c, bwf[nt][2], a, 0, 0, 0);
        a = __builtin_amdgcn_mfma_f32_16x16x32_bf16(o1c, bwf[nt][3], a, 0, 0, 0);
        a = __builtin_amdgcn_mfma_f32_16x16x32_bf16(ah0, bwhh[nt][0], a, 0, 0, 0);
        a = __builtin_amdgcn_mfma_f32_16x16x32_bf16(ah1, bwhh[nt][1], a, 0, 0, 0);
        acc[nt] = a;
      }
      #pragma unroll
      for (int rr = 0; rr < 4; ++rr) {
        float si = sigm(acc[0][rr]);
        float sf = sigm(acc[1][rr]);
        float gg = ftanh(acc[2][rr]);
        float so_ = sigm(acc[3][rr]);
        cr[rr] = sf * cr[rr] + si * gg;
        float hvv = so_ * ftanh(cr[rr]);
        h_lds[cur ^ 1][q4 * 4 + rr][hs0 + c16] = f2bf(hvv);
      }
      __syncthreads();
      cur ^= 1;
      s0c = s0n; s1c = s1n; o0c = o0n; o1c = o1n;
    }
  }
  bf16x8 fh0 = *(const bf16x8*)&h_lds[cur][c16][q4 * 8];
  bf16x8 fh1 = *(const bf16x8*)&h_lds[cur][c16][32 + q4 * 8];
  if (which == 0) {
    bf16x8 bm1[2];
    #pragma unroll
    for (int kf = 0; kf < 2; ++kf) {
      const float* wp = Wma1 + (hs0 + c16) * 64 + kf * 32 + q4 * 8;
      bf16x8 bb;
      #pragma unroll
      for (int j = 0; j < 8; ++j) bb[j] = (short)f2bf(wp[j]);
      bm1[kf] = bb;
    }
    float bs = bma1[hs0 + c16];
    f32x4 acc = {bs, bs, bs, bs};
    acc = __builtin_amdgcn_mfma_f32_16x16x32_bf16(fh0, bm1[0], acc, 0, 0, 0);
    acc = __builtin_amdgcn_mfma_f32_16x16x32_bf16(fh1, bm1[1], acc, 0, 0, 0);
    #pragma unroll
    for (int rr = 0; rr < 4; ++rr)
      ha_lds[q4 * 4 + rr][hs0 + c16] = f2bf(ftanh(acc[rr]));
    __syncthreads();
    if (w == 0) {
      bf16x8 af0 = *(const bf16x8*)&ha_lds[c16][q4 * 8];
      bf16x8 af1 = *(const bf16x8*)&ha_lds[c16][32 + q4 * 8];
      const bf16x8 z8 = {0, 0, 0, 0, 0, 0, 0, 0};
      bf16x8 bw2[2] = {z8, z8};
      float bs2 = 0.f;
      if (c16 < 15) {
        #pragma unroll
        for (int kf = 0; kf < 2; ++kf) {
          const float* wp = Wma2 + c16 * 64 + kf * 32 + q4 * 8;
          bf16x8 bb;
          #pragma unroll
          for (int j = 0; j < 8; ++j) bb[j] = (short)f2bf(wp[j]);
          bw2[kf] = bb;
        }
        bs2 = bma2[c16];
      }
      f32x4 acc2 = {bs2, bs2, bs2, bs2};
      acc2 = __builtin_amdgcn_mfma_f32_16x16x32_bf16(af0, bw2[0], acc2, 0, 0, 0);
      acc2 = __builtin_amdgcn_mfma_f32_16x16x32_bf16(af1, bw2[1], acc2, 0, 0, 0);
      #pragma unroll
      for (int rr = 0; rr < 4; ++rr)
        logit_lds[q4 * 4 + rr][c16] = acc2[rr];
    }
    __syncthreads();
    if (tid < 48) {
      int useq = tid & 15, t = tid >> 4;
      int n = seq0 + useq;
      float l0 = logit_lds[useq][t * 5 + 0], l1 = logit_lds[useq][t * 5 + 1];
      float l2 = logit_lds[useq][t * 5 + 2], l3 = logit_lds[useq][t * 5 + 3];
      float l4 = logit_lds[useq][t * 5 + 4];
      float mx = fmaxf(fmaxf(fmaxf(l0, l1), fmaxf(l2, l3)), l4);
      float sm = __expf(l0 - mx) + __expf(l1 - mx) + __expf(l2 - mx) +
                 __expf(l3 - mx) + __expf(l4 - mx);
      float lse = __logf(sm) + mx;
      int a = action[n * 3 + t];
      float lp0 = l0 - lse, lp1 = l1 - lse, lp2 = l2 - lse, lp3 = l3 - lse, lp4 = l4 - lse;
      float lpsel = logit_lds[useq][t * 5 + a] - lse;
      float ent = -(__expf(lp0) * lp0 + __expf(lp1) * lp1 + __expf(lp2) * lp2 +
                    __expf(lp3) * lp3 + __expf(lp4) * lp4);
      grp_lds[useq][t] = lpsel;
      grp_lds[useq][4 + t] = ent;
      out[n * 3 + t] = (float)a;
    }
    __syncthreads();
    if (tid < 16) {
      int n = seq0 + tid;
      out[6144 + n] = grp_lds[tid][0] + grp_lds[tid][1] + grp_lds[tid][2];
      out[8192 + n] = grp_lds[tid][4] + grp_lds[tid][5] + grp_lds[tid][6];
    }
  } else {
    bf16x8 bm1[2];
    #pragma unroll
    for (int kf = 0; kf < 2; ++kf) {
      const float* wp = Wmc1 + (hs0 + c16) * 64 + kf * 32 + q4 * 8;
      bf16x8 bb;
      #pragma unroll
      for (int j = 0; j < 8; ++j) bb[j] = (short)f2bf(wp[j]);
      bm1[kf] = bb;
    }
    float bs = bmc1[hs0 + c16];
    f32x4 acc = {bs, bs, bs, bs};
    acc = __builtin_amdgcn_mfma_f32_16x16x32_bf16(fh0, bm1[0], acc, 0, 0, 0);
    acc = __builtin_amdgcn_mfma_f32_16x16x32_bf16(fh1, bm1[1], acc, 0, 0, 0);
    float wv2 = Wmc2[hs0 + c16];
    float pv[4];
    #pragma unroll
    for (int rr = 0; rr < 4; ++rr) pv[rr] = ftanh(acc[rr]) * wv2;
    #pragma unroll
    for (int rr = 0; rr < 4; ++rr) {
      pv[rr] += __shfl_xor(pv[rr], 1);
      pv[rr] += __shfl_xor(pv[rr], 2);
      pv[rr] += __shfl_xor(pv[rr], 4);
      pv[rr] += __shfl_xor(pv[rr], 8);
    }
    if (c16 == 0) {
      #pragma unroll
      for (int rr = 0; rr < 4; ++rr) val_lds[q4 * 4 + rr][w] = pv[rr];
    }
    __syncthreads();
    if (tid < 16) {
      int n = seq0 + tid;
      out[10240 + n] = val_lds[tid][0] + val_lds[tid][1] + val_lds[tid][2] +
                       val_lds[tid][3] + bmc2[0];
    }
  }
}

extern "C" void kernel_launch(void* const* d_in, const int* in_sizes, int n_in,
                              void* d_out, int out_size, void* d_ws, size_t ws_size,
                              hipStream_t stream) {
  const float* x_actor = (const float*)d_in[0];
  const int* action = (const int*)d_in[2];
  const int* Gmat  = (const int*)d_in[3];
  const float* Wa = (const float*)d_in[4];  const float* ba = (const float*)d_in[5];
  const float* Wg = (const float*)d_in[6];  const float* bg = (const float*)d_in[7];
  const float* Qw = (const float*)d_in[8];  const float* Kw = (const float*)d_in[9];
  const float* W2 = (const float*)d_in[10]; const float* b2 = (const float*)d_in[11];
  const float* Wih_a = (const float*)d_in[12]; const float* Whh_a = (const float*)d_in[13];
  const float* bih_a = (const float*)d_in[14]; const float* bhh_a = (const float*)d_in[15];
  const float* Wih_c = (const float*)d_in[16]; const float* Whh_c = (const float*)d_in[17];
  const float* bih_c = (const float*)d_in[18]; const float* bhh_c = (const float*)d_in[19];
  const float* Wma1 = (const float*)d_in[20]; const float* bma1 = (const float*)d_in[21];
  const float* Wma2 = (const float*)d_in[22]; const float* bma2 = (const float*)d_in[23];
  const float* Wmc1 = (const float*)d_in[24]; const float* bmc1 = (const float*)d_in[25];
  const float* Wmc2 = (const float*)d_in[26]; const float* bmc2 = (const float*)d_in[27];

  unsigned short* us = (unsigned short*)d_ws;
  unsigned short* a_lin_bf = us;
  unsigned short* s_b  = us + 2097152;
  unsigned short* q_b  = us + 4194304;
  unsigned short* k_b  = us + 6291456;
  unsigned short* sT_b = us + 8388608;
  unsigned short* so_b = us + 10485760;
  unsigned short* Wfold_b = us + 12582912;
  unsigned short* Whha_b  = us + 12615680;
  unsigned short* Whhc_b  = us + 12632064;
  unsigned short* Wiha_b  = us + 12648448;
  unsigned short* WQ_b    = us + 12664832;
  unsigned short* WK_b    = us + 12668928;
  unsigned short* Wab_b   = us + 12673024;
  float* fb = (float*)(us + 12681216);
  float* bias_fold = fb;
  float* bqk = fb + 256;
  unsigned* gmask = (unsigned*)(fb + 384);
  float* out = (float*)d_out;

  void* args[] = {
    (void*)&x_actor, (void*)&Wa, (void*)&Wg, (void*)&ba, (void*)&bg,
    (void*)&Qw, (void*)&Kw, (void*)&Gmat, (void*)&Wih_c, (void*)&W2, (void*)&b2,
    (void*)&Whh_a, (void*)&Whh_c, (void*)&Wih_a,
    (void*)&bih_a, (void*)&bhh_a, (void*)&bih_c, (void*)&bhh_c, (void*)&action,
    (void*)&Wma1, (void*)&bma1, (void*)&Wma2, (void*)&bma2,
    (void*)&Wmc1, (void*)&bmc1, (void*)&Wmc2, (void*)&bmc2,
    (void*)&WQ_b, (void*)&WK_b, (void*)&bqk, (void*)&Wab_b,
    (void*)&a_lin_bf, (void*)&s_b, (void*)&q_b, (void*)&k_b, (void*)&sT_b,
    (void*)&so_b, (void*)&Wfold_b, (void*)&bias_fold, (void*)&gmask,
    (void*)&Whha_b, (void*)&Whhc_b, (void*)&Wiha_b, (void*)&out};
  hipError_t err = hipLaunchCooperativeKernel(
      reinterpret_cast<void*>(kMega), dim3(256), dim3(512), args, 0u, stream);
  if (err != hipSuccess) {
    // fallback: proven 4-kernel path
    kP_pre<<<35, 256, 0, stream>>>(Wa, Wg, bg, Qw, Kw, WQ_b, WK_b, bqk, Wab_b);
    kA_lin<<<729, 256, 0, stream>>>(x_actor, Wab_b, WQ_b, WK_b, ba, bg, bqk,
                                    Gmat, Wih_c, W2, b2, Whh_a, Whh_c, Wih_a,
                                    a_lin_bf, s_b, q_b, k_b, sT_b,
                                    Wfold_b, bias_fold, gmask,
                                    Whha_b, Whhc_b, Wiha_b);
    kB_attn<<<512, 512, 0, stream>>>(q_b, k_b, sT_b, gmask, so_b);
    kR_lstm<<<256, 256, 0, stream>>>(a_lin_bf, s_b, so_b, Wfold_b, bias_fold,
                                     Wiha_b, Whha_b, Whhc_b,
                                     bih_a, bhh_a, bih_c, bhh_c,
                                     action, Wma1, bma1, Wma2, bma2,
                                     Wmc1, bmc1, Wmc2, bmc2, out);
  }
}

// Round 13
// 67.695 us; speedup vs baseline: 2.5050x; 2.5050x over previous
//
#include <hip/hip_runtime.h>
#include <math.h>

#define B_ 8
#define L_ 16
#define M_ 256
#define H_ 53
#define HID_ 64
#define LB_ 128  // L_*B_
#define SCALE_ 0.08838834764831845f

typedef __attribute__((ext_vector_type(8))) short bf16x8;
typedef __attribute__((ext_vector_type(4))) float f32x4;

__device__ inline unsigned short f2bf(float f) {
  unsigned u = __builtin_bit_cast(unsigned, f);
  unsigned r = (u + 0x7FFFu + ((u >> 16) & 1u)) >> 16;
  return (unsigned short)r;
}
__device__ inline float bf2f(unsigned short u) {
  unsigned v = ((unsigned)u) << 16;
  return __builtin_bit_cast(float, v);
}
__device__ inline float sigm(float x) { return __builtin_amdgcn_rcpf(1.f + __expf(-x)); }
__device__ inline float ftanh(float x) { return 1.f - 2.f * __builtin_amdgcn_rcpf(1.f + __expf(2.f * x)); }

// ---------------- kP: only what kA consumes (WQ/WK, bqk, Wab) ----------------
__global__ __launch_bounds__(256) void kP_pre(
    const float* __restrict__ Wa, const float* __restrict__ Wg,
    const float* __restrict__ bg,
    const float* __restrict__ Qw, const float* __restrict__ Kw,
    unsigned short* __restrict__ WQ_b, unsigned short* __restrict__ WK_b,
    float* __restrict__ bqk, unsigned short* __restrict__ Wab_b) {
  int blk = blockIdx.x, tid = threadIdx.x;
  if (blk < 32) {                       // WQ/WK [64][64] (f32 math, scale folded into WQ)
    int idx = blk * 256 + tid;
    int which = idx >> 12, n = (idx >> 6) & 63, j = idx & 63;
    const float* Mm = which ? Kw : Qw;
    float acc = 0.f;
    if (j < 53) {
      for (int e = 0; e < 64; ++e) acc = fmaf(Mm[e * 64 + n], Wg[e * 53 + j], acc);
      if (which == 0) acc *= SCALE_;
    }
    (which ? WK_b : WQ_b)[n * 64 + j] = f2bf(acc);
  } else if (blk == 32) {               // bqk[128]
    if (tid < 128) {
      int which = tid >> 6, n = tid & 63;
      const float* Mm = which ? Kw : Qw;
      float acc = 0.f;
      for (int e = 0; e < 64; ++e) acc = fmaf(bg[e], Mm[e * 64 + n], acc);
      if (which == 0) acc *= SCALE_;
      bqk[tid] = acc;
    }
  } else {                              // Wab_b [128][64] bf16 padded (2 blocks)
    int base = (blk - 33) * 4096;
    #pragma unroll
    for (int k = 0; k < 16; ++k) {
      int idx = base + k * 256 + tid;   // 0..8191
      int n = idx >> 6, j = idx & 63;
      float v = 0.f;
      if (j < 53) v = (n < 64) ? Wa[n * 53 + j] : Wg[(n - 64) * 53 + j];
      Wab_b[idx] = f2bf(v);
    }
  }
}

// ---------------- Kernel A: lean MFMA projections + one-time extras ----------------
#define WS 68
#define OS 268
__global__ __launch_bounds__(256, 2) void kA_lin(const float* __restrict__ x,
    const unsigned short* __restrict__ Wab_b,
    const unsigned short* __restrict__ WQ_b, const unsigned short* __restrict__ WK_b,
    const float* __restrict__ ba, const float* __restrict__ bg,
    const float* __restrict__ bqk,
    const int* __restrict__ Gmat, const float* __restrict__ Wih_c,
    const float* __restrict__ W2, const float* __restrict__ b2,
    const float* __restrict__ Whh_a, const float* __restrict__ Whh_c,
    const float* __restrict__ Wih_a,
    unsigned short* __restrict__ a_lin_bf, unsigned short* __restrict__ s_b,
    unsigned short* __restrict__ q_b, unsigned short* __restrict__ k_b,
    unsigned short* __restrict__ sT_b,
    unsigned short* __restrict__ Wfold_b, float* __restrict__ bias_fold,
    unsigned* __restrict__ gmask,
    unsigned short* __restrict__ Whha_b, unsigned short* __restrict__ Whhc_b,
    unsigned short* __restrict__ Wiha_b) {
  int tid = threadIdx.x, blk = blockIdx.x;
  if (blk >= 512) {
    int b2k = blk - 512;
    if (b2k < 128) {               // Wfold[256][128]
      int idx = b2k * 256 + tid;
      int n = idx >> 7, t = idx & 127;
      float acc = 0.f;
      for (int e = 0; e < 64; ++e) acc = fmaf(Wih_c[n * 64 + e], W2[e * 128 + t], acc);
      Wfold_b[idx] = f2bf(acc);
    } else if (b2k < 192) {        // gmask
      int l = (b2k - 128) * 4 + (tid >> 6);
      int ln = tid & 63;
      #pragma unroll
      for (int c = 0; c < 4; ++c) {
        int gv = Gmat[l * 256 + c * 64 + ln];
        unsigned long long msk = __ballot(gv > 0);
        if (ln == 0) {
          gmask[l * 8 + c * 2] = (unsigned)msk;
          gmask[l * 8 + c * 2 + 1] = (unsigned)(msk >> 32);
        }
      }
    } else if (b2k == 192) {       // bias_fold[256]
      float acc = 0.f;
      for (int e = 0; e < 64; ++e) acc = fmaf(Wih_c[tid * 64 + e], b2[e], acc);
      bias_fold[tid] = acc;
    } else {                       // bf16 casts: Whh_a | Whh_c | Wih_a
      int base = (b2k - 193) * 2048;
      #pragma unroll
      for (int k = 0; k < 8; ++k) {
        int idx = base + k * 256 + tid;
        if (idx < 16384) Whha_b[idx] = f2bf(Whh_a[idx]);
        else if (idx < 32768) Whhc_b[idx - 16384] = f2bf(Whh_c[idx - 16384]);
        else Wiha_b[idx - 32768] = f2bf(Wih_a[idx - 32768]);
      }
    }
    return;
  }
  __shared__ __attribute__((aligned(16))) char smem[70144];
  float* x_raw = (float*)smem;                               // 13568 B (aliased w/ out_lds)
  unsigned short* out_lds = (unsigned short*)smem;           // [64][268] = 34304 B
  unsigned short* w_lds = (unsigned short*)(smem + 34304);   // [256][68] = 34816 B
  float* bias_lds = (float*)(smem + 69120);                  // 1024 B
  int row0 = blk * 64;
  int lbA = row0 >> 8, m0 = row0 & 255;
  int lA = lbA >> 3, bA = lbA & 7;
  // stage x region raw (contiguous 64*53 f32, 16B aligned)
  {
    const uint4* xs = (const uint4*)(x + ((bA * L_ + lA) * M_ + m0) * H_);
    uint4* xr = (uint4*)x_raw;
    #pragma unroll
    for (int k = 0; k < 4; ++k) {
      int i = k * 256 + tid;
      if (i < 848) xr[i] = xs[i];
    }
  }
  // stage weights (all uint4, coalesced): rows 0-127 Wab, 128-191 WQ, 192-255 WK
  #pragma unroll
  for (int k = 0; k < 8; ++k) {
    int i = k * 256 + tid;
    int n = i >> 3, c8 = (i & 7) * 8;
    const unsigned short* src = n < 128 ? Wab_b + n * 64
                              : (n < 192 ? WQ_b + (n - 128) * 64 : WK_b + (n - 192) * 64);
    *(uint4*)&w_lds[n * WS + c8] = *(const uint4*)(src + c8);
  }
  {
    float bv;
    if (tid < 64) bv = ba[tid];
    else if (tid < 128) bv = bg[tid - 64];
    else bv = bqk[tid - 128];
    bias_lds[tid] = bv;
  }
  __syncthreads();
  int lane = tid & 63, w = tid >> 6;
  int c16 = lane & 15, q4 = lane >> 4;
  int lrow = w * 16 + c16;
  bf16x8 a0, a1;
  #pragma unroll
  for (int e = 0; e < 8; ++e)
    a0[e] = (short)f2bf(x_raw[lrow * H_ + q4 * 8 + e]);
  #pragma unroll
  for (int e = 0; e < 8; ++e) {
    int c = 32 + q4 * 8 + e;
    a1[e] = (c < H_) ? (short)f2bf(x_raw[lrow * H_ + c]) : (short)0;
  }
  __syncthreads();   // x_raw reads done; out_lds may overwrite
  #pragma unroll
  for (int nt = 0; nt < 16; ++nt) {
    bf16x8 b0 = *(const bf16x8*)&w_lds[(nt * 16 + c16) * WS + q4 * 8];
    bf16x8 b1 = *(const bf16x8*)&w_lds[(nt * 16 + c16) * WS + 32 + q4 * 8];
    float bs = bias_lds[nt * 16 + c16];
    f32x4 acc = {bs, bs, bs, bs};
    acc = __builtin_amdgcn_mfma_f32_16x16x32_bf16(a0, b0, acc, 0, 0, 0);
    acc = __builtin_amdgcn_mfma_f32_16x16x32_bf16(a1, b1, acc, 0, 0, 0);
    #pragma unroll
    for (int rr = 0; rr < 4; ++rr)
      out_lds[(w * 16 + q4 * 4 + rr) * OS + nt * 16 + c16] = f2bf(acc[rr]);
  }
  __syncthreads();
  #pragma unroll
  for (int k = 0; k < 8; ++k) {
    int i = k * 256 + tid;
    int r = i >> 5, seg = i & 31;
    int which = seg >> 3, n8 = (seg & 7) * 8;
    uint4 v = *(const uint4*)&out_lds[r * OS + which * 64 + n8];
    unsigned short* dst = which == 0 ? a_lin_bf : which == 1 ? s_b : which == 2 ? q_b : k_b;
    *(uint4*)&dst[(row0 + r) * 64 + n8] = v;
  }
  #pragma unroll
  for (int k = 0; k < 4; ++k) {
    int i = k * 256 + tid;
    int e = i >> 4, mc = i & 15;
    ushort4 v;
    v.x = out_lds[(mc * 4 + 0) * OS + 64 + e];
    v.y = out_lds[(mc * 4 + 1) * OS + 64 + e];
    v.z = out_lds[(mc * 4 + 2) * OS + 64 + e];
    v.w = out_lds[(mc * 4 + 3) * OS + 64 + e];
    *(ushort4*)&sT_b[(lbA * 64 + e) * 256 + m0 + mc * 4] = v;
  }
}

// ---------------- Kernel B: LDS-staged MFMA attention, XCD-swizzled ----------------
__global__ __launch_bounds__(512, 4) void kB_attn(
    const unsigned short* __restrict__ qb, const unsigned short* __restrict__ kb,
    const unsigned short* __restrict__ sT, const unsigned* __restrict__ gmask,
    unsigned short* __restrict__ so_b) {
  __shared__ __attribute__((aligned(16))) unsigned short k_lds[256 * 68];
  __shared__ __attribute__((aligned(16))) unsigned short sT_lds[64 * 280];
  int bid = blockIdx.x;
  int xcd = bid & 7;
  int rest = bid >> 3;
  int l0 = (rest & 3) << 6;
  int lb = (rest >> 2) * 8 + xcd;     // quarters of lb share XCD lb&7
  int tid = threadIdx.x;
  int kbase = lb * 256;
  for (int i = tid; i < 2048; i += 512) {
    int s = i >> 3, e8 = (i & 7) * 8;
    *(uint4*)&k_lds[s * 68 + e8] = *(const uint4*)(kb + (kbase + s) * 64 + e8);
  }
  for (int i = tid; i < 2048; i += 512) {
    int e = i >> 5, m8 = (i & 31) * 8;
    *(uint4*)&sT_lds[e * 280 + m8] = *(const uint4*)(sT + (lb * 64 + e) * 256 + m8);
  }
  int lane = tid & 63, w = tid >> 6;
  int c16 = lane & 15, q4 = lane >> 4;
  int lrow0 = (w >> 1) * 16;
  int h0 = (w & 1) * 2;
  int lrow = lb * 256 + l0 + lrow0;
  const bf16x8 z8 = {0, 0, 0, 0, 0, 0, 0, 0};
  bf16x8 bq[2];
  #pragma unroll
  for (int hp = 0; hp < 2; ++hp) {
    int h = h0 + hp;
    bq[hp] = (q4 < 2) ? *(const bf16x8*)(qb + (lrow + c16) * 64 + h * 16 + q4 * 8) : z8;
  }
  unsigned gwv[8];
  #pragma unroll
  for (int sp = 0; sp < 8; ++sp) gwv[sp] = gmask[(l0 + lrow0 + c16) * 8 + sp];
  __syncthreads();
  f32x4 accO[2];
  float sumh[2];
  #pragma unroll
  for (int hp = 0; hp < 2; ++hp) { accO[hp] = (f32x4){0.f, 0.f, 0.f, 0.f}; sumh[hp] = 0.f; }

  #pragma unroll
  for (int sp = 0; sp < 8; ++sp) {
    unsigned gw = gwv[sp];
    #pragma unroll
    for (int hp = 0; hp < 2; ++hp) {
      int h = h0 + hp;
      unsigned pk0A, pk1A, pk0B, pk1B;
      #pragma unroll
      for (int tp = 0; tp < 2; ++tp) {
        int t = sp * 2 + tp;
        bf16x8 ka = z8;
        if (q4 < 2) ka = *(const bf16x8*)&k_lds[(t * 16 + c16) * 68 + h * 16 + q4 * 8];
        f32x4 d = __builtin_amdgcn_mfma_f32_16x16x32_bf16(ka, bq[hp], (f32x4){0.f, 0.f, 0.f, 0.f}, 0, 0, 0);
        int bitbase = tp * 16 + q4 * 4;
        float p0 = ((gw >> (bitbase + 0)) & 1u) ? __expf(d[0]) : 0.f;
        float p1 = ((gw >> (bitbase + 1)) & 1u) ? __expf(d[1]) : 0.f;
        float p2 = ((gw >> (bitbase + 2)) & 1u) ? __expf(d[2]) : 0.f;
        float p3 = ((gw >> (bitbase + 3)) & 1u) ? __expf(d[3]) : 0.f;
        sumh[hp] += (p0 + p1) + (p2 + p3);
        unsigned lo = (unsigned)f2bf(p0) | ((unsigned)f2bf(p1) << 16);
        unsigned hi = (unsigned)f2bf(p2) | ((unsigned)f2bf(p3) << 16);
        if (tp == 0) { pk0A = lo; pk1A = hi; } else { pk0B = lo; pk1B = hi; }
      }
      int srcA = ((q4 & 1) * 2) * 16 + c16, srcB = srcA + 16;
      unsigned g0A = (unsigned)__shfl((int)pk0A, srcA);
      unsigned g1A = (unsigned)__shfl((int)pk1A, srcA);
      unsigned g2A = (unsigned)__shfl((int)pk0A, srcB);
      unsigned g3A = (unsigned)__shfl((int)pk1A, srcB);
      unsigned g0B = (unsigned)__shfl((int)pk0B, srcA);
      unsigned g1B = (unsigned)__shfl((int)pk1B, srcA);
      unsigned g2B = (unsigned)__shfl((int)pk0B, srcB);
      unsigned g3B = (unsigned)__shfl((int)pk1B, srcB);
      bool useB = (q4 >= 2);
      uint4 av;
      av.x = useB ? g0B : g0A;
      av.y = useB ? g1B : g1A;
      av.z = useB ? g2B : g2A;
      av.w = useB ? g3B : g3A;
      bf16x8 af = __builtin_bit_cast(bf16x8, av);
      bf16x8 bs = *(const bf16x8*)&sT_lds[(h * 16 + c16) * 280 + sp * 32 + q4 * 8];
      accO[hp] = __builtin_amdgcn_mfma_f32_16x16x32_bf16(af, bs, accO[hp], 0, 0, 0);
    }
  }
  #pragma unroll
  for (int hp = 0; hp < 2; ++hp) {
    int h = h0 + hp;
    float s = sumh[hp];
    s += __shfl_xor(s, 16);
    s += __shfl_xor(s, 32);
    #pragma unroll
    for (int r = 0; r < 4; ++r) {
      float sv = __shfl(s, q4 * 4 + r);
      float o = accO[hp][r] / sv;
      so_b[(lb * 256 + l0 + lrow0 + q4 * 4 + r) * 64 + h * 16 + c16] = f2bf(o);
    }
  }
}

// ---------------- kR: LSTM recurrence (1 barrier/step) + fused heads ----------------
__global__ __launch_bounds__(256, 1) void kR_lstm(
    const unsigned short* __restrict__ a_lin_bf,
    const unsigned short* __restrict__ s_b, const unsigned short* __restrict__ so_b,
    const unsigned short* __restrict__ Wfold_b, const float* __restrict__ bias_fold,
    const unsigned short* __restrict__ Wiha_b,
    const unsigned short* __restrict__ Whha_b, const unsigned short* __restrict__ Whhc_b,
    const float* __restrict__ bih_a, const float* __restrict__ bhh_a,
    const float* __restrict__ bih_c, const float* __restrict__ bhh_c,
    const int* __restrict__ action,
    const float* __restrict__ Wma1, const float* __restrict__ bma1,
    const float* __restrict__ Wma2, const float* __restrict__ bma2,
    const float* __restrict__ Wmc1, const float* __restrict__ bmc1,
    const float* __restrict__ Wmc2, const float* __restrict__ bmc2,
    float* __restrict__ out) {
  int blk = blockIdx.x;
  int which = blk >> 7, g = blk & 127;
  int seq0 = g * 16;
  int b = seq0 >> 8, m0 = seq0 & 255;
  __shared__ __attribute__((aligned(16))) unsigned short h_lds[2][16][72];
  __shared__ __attribute__((aligned(16))) unsigned short ha_lds[16][72];
  __shared__ float logit_lds[16][16];
  __shared__ float grp_lds[16][8];
  __shared__ float val_lds[16][4];
  int tid = threadIdx.x;
  int lane = tid & 63, w = tid >> 6;
  int c16 = lane & 15, q4 = lane >> 4;
  int hs0 = w * 16;
  const unsigned short* Whh_b = which ? Whhc_b : Whha_b;
  const float* bih = which ? bih_c : bih_a;
  const float* bhh = which ? bhh_c : bhh_a;
  bf16x8 bwhh[4][2];
  float bias[4];
  #pragma unroll
  for (int nt = 0; nt < 4; ++nt) {
    int n = nt * 64 + hs0 + c16;
    bias[nt] = bih[n] + bhh[n] + (which ? bias_fold[n] : 0.f);
    #pragma unroll
    for (int kf = 0; kf < 2; ++kf)
      bwhh[nt][kf] = *(const bf16x8*)(Whh_b + n * 64 + kf * 32 + q4 * 8);
  }
  for (int i = tid; i < 576; i += 256) ((unsigned*)h_lds)[i] = 0u;
  float cr[4] = {0.f, 0.f, 0.f, 0.f};
  const int STEP = 2048 * 64;
  __syncthreads();
  int cur = 0;
  if (which == 0) {
    bf16x8 bwin[4][2];
    #pragma unroll
    for (int nt = 0; nt < 4; ++nt) {
      int n = nt * 64 + hs0 + c16;
      #pragma unroll
      for (int kf = 0; kf < 2; ++kf)
        bwin[nt][kf] = *(const bf16x8*)(Wiha_b + n * 64 + kf * 32 + q4 * 8);
    }
    const unsigned short* inb = a_lin_bf + (b * 256 + m0 + c16) * 64;
    bf16x8 i0c = *(const bf16x8*)(inb + q4 * 8);
    bf16x8 i1c = *(const bf16x8*)(inb + 32 + q4 * 8);
    for (int l = 0; l < L_; ++l) {
      bf16x8 i0n = i0c, i1n = i1c;
      if (l < L_ - 1) {
        i0n = *(const bf16x8*)(inb + (l + 1) * STEP + q4 * 8);
        i1n = *(const bf16x8*)(inb + (l + 1) * STEP + 32 + q4 * 8);
      }
      bf16x8 ah0 = *(const bf16x8*)&h_lds[cur][c16][q4 * 8];
      bf16x8 ah1 = *(const bf16x8*)&h_lds[cur][c16][32 + q4 * 8];
      f32x4 acc[4];
      #pragma unroll
      for (int nt = 0; nt < 4; ++nt) {
        f32x4 a = {bias[nt], bias[nt], bias[nt], bias[nt]};
        a = __builtin_amdgcn_mfma_f32_16x16x32_bf16(i0c, bwin[nt][0], a, 0, 0, 0);
        a = __builtin_amdgcn_mfma_f32_16x16x32_bf16(i1c, bwin[nt][1], a, 0, 0, 0);
        a = __builtin_amdgcn_mfma_f32_16x16x32_bf16(ah0, bwhh[nt][0], a, 0, 0, 0);
        a = __builtin_amdgcn_mfma_f32_16x16x32_bf16(ah1, bwhh[nt][1], a, 0, 0, 0);
        acc[nt] = a;
      }
      #pragma unroll
      for (int rr = 0; rr < 4; ++rr) {
        float si = sigm(acc[0][rr]);
        float sf = sigm(acc[1][rr]);
        float gg = ftanh(acc[2][rr]);
        float so_ = sigm(acc[3][rr]);
        cr[rr] = sf * cr[rr] + si * gg;
        float hvv = so_ * ftanh(cr[rr]);
        h_lds[cur ^ 1][q4 * 4 + rr][hs0 + c16] = f2bf(hvv);
      }
      __syncthreads();
      cur ^= 1;
      i0c = i0n; i1c = i1n;
    }
  } else {
    bf16x8 bwf[4][4];
    #pragma unroll
    for (int nt = 0; nt < 4; ++nt) {
      int n = nt * 64 + hs0 + c16;
      #pragma unroll
      for (int kc = 0; kc < 4; ++kc)
        bwf[nt][kc] = *(const bf16x8*)(Wfold_b + n * 128 + kc * 32 + q4 * 8);
    }
    const unsigned short* sbB = s_b + (b * 256 + m0 + c16) * 64;
    const unsigned short* soB = so_b + (b * 256 + m0 + c16) * 64;
    bf16x8 s0c = *(const bf16x8*)(sbB + q4 * 8);
    bf16x8 s1c = *(const bf16x8*)(sbB + 32 + q4 * 8);
    bf16x8 o0c = *(const bf16x8*)(soB + q4 * 8);
    bf16x8 o1c = *(const bf16x8*)(soB + 32 + q4 * 8);
    for (int l = 0; l < L_; ++l) {
      bf16x8 s0n = s0c, s1n = s1c, o0n = o0c, o1n = o1c;
      if (l < L_ - 1) {
        s0n = *(const bf16x8*)(sbB + (l + 1) * STEP + q4 * 8);
        s1n = *(const bf16x8*)(sbB + (l + 1) * STEP + 32 + q4 * 8);
        o0n = *(const bf16x8*)(soB + (l + 1) * STEP + q4 * 8);
        o1n = *(const bf16x8*)(soB + (l + 1) * STEP + 32 + q4 * 8);
      }
      bf16x8 ah0 = *(const bf16x8*)&h_lds[cur][c16][q4 * 8];
      bf16x8 ah1 = *(const bf16x8*)&h_lds[cur][c16][32 + q4 * 8];
      f32x4 acc[4];
      #pragma unroll
      for (int nt = 0; nt < 4; ++nt) {
        f32x4 a = {bias[nt], bias[nt], bias[nt], bias[nt]};
        a = __builtin_amdgcn_mfma_f32_16x16x32_bf16(s0c, bwf[nt][0], a, 0, 0, 0);
        a = __builtin_amdgcn_mfma_f32_16x16x32_bf16(s1c, bwf[nt][1], a, 0, 0, 0);
        a = __builtin_amdgcn_mfma_f32_16x16x32_bf16(o0c, bwf[nt][2], a, 0, 0, 0);
        a = __builtin_amdgcn_mfma_f32_16x16x32_bf16(o1c, bwf[nt][3], a, 0, 0, 0);
        a = __builtin_amdgcn_mfma_f32_16x16x32_bf16(ah0, bwhh[nt][0], a, 0, 0, 0);
        a = __builtin_amdgcn_mfma_f32_16x16x32_bf16(ah1, bwhh[nt][1], a, 0, 0, 0);
        acc[nt] = a;
      }
      #pragma unroll
      for (int rr = 0; rr < 4; ++rr) {
        float si = sigm(acc[0][rr]);
        float sf = sigm(acc[1][rr]);
        float gg = ftanh(acc[2][rr]);
        float so_ = sigm(acc[3][rr]);
        cr[rr] = sf * cr[rr] + si * gg;
        float hvv = so_ * ftanh(cr[rr]);
        h_lds[cur ^ 1][q4 * 4 + rr][hs0 + c16] = f2bf(hvv);
      }
      __syncthreads();
      cur ^= 1;
      s0c = s0n; s1c = s1n; o0c = o0n; o1c = o1n;
    }
  }
  bf16x8 fh0 = *(const bf16x8*)&h_lds[cur][c16][q4 * 8];
  bf16x8 fh1 = *(const bf16x8*)&h_lds[cur][c16][32 + q4 * 8];
  if (which == 0) {
    bf16x8 bm1[2];
    #pragma unroll
    for (int kf = 0; kf < 2; ++kf) {
      const float* wp = Wma1 + (hs0 + c16) * 64 + kf * 32 + q4 * 8;
      bf16x8 bb;
      #pragma unroll
      for (int j = 0; j < 8; ++j) bb[j] = (short)f2bf(wp[j]);
      bm1[kf] = bb;
    }
    float bs = bma1[hs0 + c16];
    f32x4 acc = {bs, bs, bs, bs};
    acc = __builtin_amdgcn_mfma_f32_16x16x32_bf16(fh0, bm1[0], acc, 0, 0, 0);
    acc = __builtin_amdgcn_mfma_f32_16x16x32_bf16(fh1, bm1[1], acc, 0, 0, 0);
    #pragma unroll
    for (int rr = 0; rr < 4; ++rr)
      ha_lds[q4 * 4 + rr][hs0 + c16] = f2bf(ftanh(acc[rr]));
    __syncthreads();
    if (w == 0) {
      bf16x8 af0 = *(const bf16x8*)&ha_lds[c16][q4 * 8];
      bf16x8 af1 = *(const bf16x8*)&ha_lds[c16][32 + q4 * 8];
      const bf16x8 z8 = {0, 0, 0, 0, 0, 0, 0, 0};
      bf16x8 bw2[2] = {z8, z8};
      float bs2 = 0.f;
      if (c16 < 15) {
        #pragma unroll
        for (int kf = 0; kf < 2; ++kf) {
          const float* wp = Wma2 + c16 * 64 + kf * 32 + q4 * 8;
          bf16x8 bb;
          #pragma unroll
          for (int j = 0; j < 8; ++j) bb[j] = (short)f2bf(wp[j]);
          bw2[kf] = bb;
        }
        bs2 = bma2[c16];
      }
      f32x4 acc2 = {bs2, bs2, bs2, bs2};
      acc2 = __builtin_amdgcn_mfma_f32_16x16x32_bf16(af0, bw2[0], acc2, 0, 0, 0);
      acc2 = __builtin_amdgcn_mfma_f32_16x16x32_bf16(af1, bw2[1], acc2, 0, 0, 0);
      #pragma unroll
      for (int rr = 0; rr < 4; ++rr)
        logit_lds[q4 * 4 + rr][c16] = acc2[rr];
    }
    __syncthreads();
    if (tid < 48) {
      int useq = tid & 15, t = tid >> 4;
      int n = seq0 + useq;
      float l0 = logit_lds[useq][t * 5 + 0], l1 = logit_lds[useq][t * 5 + 1];
      float l2 = logit_lds[useq][t * 5 + 2], l3 = logit_lds[useq][t * 5 + 3];
      float l4 = logit_lds[useq][t * 5 + 4];
      float mx = fmaxf(fmaxf(fmaxf(l0, l1), fmaxf(l2, l3)), l4);
      float sm = __expf(l0 - mx) + __expf(l1 - mx) + __expf(l2 - mx) +
                 __expf(l3 - mx) + __expf(l4 - mx);
      float lse = __logf(sm) + mx;
      int a = action[n * 3 + t];
      float lp0 = l0 - lse, lp1 = l1 - lse, lp2 = l2 - lse, lp3 = l3 - lse, lp4 = l4 - lse;
      float lpsel = logit_lds[useq][t * 5 + a] - lse;
      float ent = -(__expf(lp0) * lp0 + __expf(lp1) * lp1 + __expf(lp2) * lp2 +
                    __expf(lp3) * lp3 + __expf(lp4) * lp4);
      grp_lds[useq][t] = lpsel;
      grp_lds[useq][4 + t] = ent;
      out[n * 3 + t] = (float)a;
    }
    __syncthreads();
    if (tid < 16) {
      int n = seq0 + tid;
      out[6144 + n] = grp_lds[tid][0] + grp_lds[tid][1] + grp_lds[tid][2];
      out[8192 + n] = grp_lds[tid][4] + grp_lds[tid][5] + grp_lds[tid][6];
    }
  } else {
    bf16x8 bm1[2];
    #pragma unroll
    for (int kf = 0; kf < 2; ++kf) {
      const float* wp = Wmc1 + (hs0 + c16) * 64 + kf * 32 + q4 * 8;
      bf16x8 bb;
      #pragma unroll
      for (int j = 0; j < 8; ++j) bb[j] = (short)f2bf(wp[j]);
      bm1[kf] = bb;
    }
    float bs = bmc1[hs0 + c16];
    f32x4 acc = {bs, bs, bs, bs};
    acc = __builtin_amdgcn_mfma_f32_16x16x32_bf16(fh0, bm1[0], acc, 0, 0, 0);
    acc = __builtin_amdgcn_mfma_f32_16x16x32_bf16(fh1, bm1[1], acc, 0, 0, 0);
    float wv2 = Wmc2[hs0 + c16];
    float pv[4];
    #pragma unroll
    for (int rr = 0; rr < 4; ++rr) pv[rr] = ftanh(acc[rr]) * wv2;
    #pragma unroll
    for (int rr = 0; rr < 4; ++rr) {
      pv[rr] += __shfl_xor(pv[rr], 1);
      pv[rr] += __shfl_xor(pv[rr], 2);
      pv[rr] += __shfl_xor(pv[rr], 4);
      pv[rr] += __shfl_xor(pv[rr], 8);
    }
    if (c16 == 0) {
      #pragma unroll
      for (int rr = 0; rr < 4; ++rr) val_lds[q4 * 4 + rr][w] = pv[rr];
    }
    __syncthreads();
    if (tid < 16) {
      int n = seq0 + tid;
      out[10240 + n] = val_lds[tid][0] + val_lds[tid][1] + val_lds[tid][2] +
                       val_lds[tid][3] + bmc2[0];
    }
  }
}

extern "C" void kernel_launch(void* const* d_in, const int* in_sizes, int n_in,
                              void* d_out, int out_size, void* d_ws, size_t ws_size,
                              hipStream_t stream) {
  const float* x_actor = (const float*)d_in[0];
  const int* action = (const int*)d_in[2];
  const int* Gmat  = (const int*)d_in[3];
  const float* Wa = (const float*)d_in[4];  const float* ba = (const float*)d_in[5];
  const float* Wg = (const float*)d_in[6];  const float* bg = (const float*)d_in[7];
  const float* Qw = (const float*)d_in[8];  const float* Kw = (const float*)d_in[9];
  const float* W2 = (const float*)d_in[10]; const float* b2 = (const float*)d_in[11];
  const float* Wih_a = (const float*)d_in[12]; const float* Whh_a = (const float*)d_in[13];
  const float* bih_a = (const float*)d_in[14]; const float* bhh_a = (const float*)d_in[15];
  const float* Wih_c = (const float*)d_in[16]; const float* Whh_c = (const float*)d_in[17];
  const float* bih_c = (const float*)d_in[18]; const float* bhh_c = (const float*)d_in[19];
  const float* Wma1 = (const float*)d_in[20]; const float* bma1 = (const float*)d_in[21];
  const float* Wma2 = (const float*)d_in[22]; const float* bma2 = (const float*)d_in[23];
  const float* Wmc1 = (const float*)d_in[24]; const float* bmc1 = (const float*)d_in[25];
  const float* Wmc2 = (const float*)d_in[26]; const float* bmc2 = (const float*)d_in[27];

  unsigned short* us = (unsigned short*)d_ws;
  unsigned short* a_lin_bf = us;                 // 2,097,152
  unsigned short* s_b  = us + 2097152;
  unsigned short* q_b  = us + 4194304;
  unsigned short* k_b  = us + 6291456;
  unsigned short* sT_b = us + 8388608;
  unsigned short* so_b = us + 10485760;
  unsigned short* Wfold_b = us + 12582912;       // 32,768
  unsigned short* Whha_b  = us + 12615680;       // 16,384
  unsigned short* Whhc_b  = us + 12632064;       // 16,384
  unsigned short* Wiha_b  = us + 12648448;       // 16,384
  unsigned short* WQ_b    = us + 12664832;       // 4,096
  unsigned short* WK_b    = us + 12668928;       // 4,096
  unsigned short* Wab_b   = us + 12673024;       // 8,192
  float* fb = (float*)(us + 12681216);           // 16B aligned
  float* bias_fold = fb;                         // 256
  float* bqk = fb + 256;                         // 128
  unsigned* gmask = (unsigned*)(fb + 384);       // 2,048
  float* out = (float*)d_out;

  kP_pre<<<35, 256, 0, stream>>>(Wa, Wg, bg, Qw, Kw, WQ_b, WK_b, bqk, Wab_b);
  kA_lin<<<729, 256, 0, stream>>>(x_actor, Wab_b, WQ_b, WK_b, ba, bg, bqk,
                                  Gmat, Wih_c, W2, b2, Whh_a, Whh_c, Wih_a,
                                  a_lin_bf, s_b, q_b, k_b, sT_b,
                                  Wfold_b, bias_fold, gmask,
                                  Whha_b, Whhc_b, Wiha_b);
  kB_attn<<<512, 512, 0, stream>>>(q_b, k_b, sT_b, gmask, so_b);
  kR_lstm<<<256, 256, 0, stream>>>(a_lin_bf, s_b, so_b, Wfold_b, bias_fold,
                                   Wiha_b, Whha_b, Whhc_b,
                                   bih_a, bhh_a, bih_c, bhh_c,
                                   action, Wma1, bma1, Wma2, bma2,
                                   Wmc1, bmc1, Wmc2, bmc2, out);
}